// Round 4
// baseline (502.413 us; speedup 1.0000x reference)
//
#include <hip/hip_runtime.h>
#include <hip/hip_bf16.h>
#include <math.h>

#define NN 262144
#define CC 512
#define BB 1024
#define EPSF 1e-5f
#define CAP 512   // LDS spg capacity (nodes/segment); overflow spills to ws

typedef float f32x4 __attribute__((ext_vector_type(4)));

__device__ __forceinline__ int lower_bound_i(const int* __restrict__ a, int n, int v) {
    int lo = 0, hi = n;
    while (lo < hi) { int mid = (lo + hi) >> 1; if (a[mid] < v) lo = mid + 1; else hi = mid; }
    return lo;
}

__device__ __forceinline__ float sigmoidf(float v) { return 1.0f / (1.0f + __expf(-v)); }

// Fused single-instruction DPP reduction steps (v_add_f32_dpp / v_max_f32_dpp).
// 0xB1 = quad_perm xor1, 0x4E = quad_perm xor2,
// 0x124 = row_ror:4, 0x128 = row_ror:8, 0x141 = row_half_mirror
template<int CTRL>
__device__ __forceinline__ float dppAdd(float v) {
    int t = __builtin_amdgcn_update_dpp(0, __float_as_int(v), CTRL, 0xf, 0xf, true);
    return v + __int_as_float(t);
}
template<int CTRL>
__device__ __forceinline__ float dppMax(float v) {
    int t = __builtin_amdgcn_update_dpp(0, __float_as_int(v), CTRL, 0xf, 0xf, true);
    return fmaxf(v, __int_as_float(t));
}

// One block = one segment at a time (4 sequential segments per block).
// P1: stats + sp_gate (spg -> LDS). F: per-segment MLPs -> per-column affine
// (coef/offs in LDS). P2: re-read x (L3-hot, ~512KB x 256 blocks = 128MB < L3),
// apply affine, write out nontemporal.
__global__ __launch_bounds__(512, 1) void kFused(
    const float* __restrict__ x, const int* __restrict__ batch,
    const float* __restrict__ cweight, const float* __restrict__ cbias,
    const float* __restrict__ sweight, const float* __restrict__ sbias,
    const float* __restrict__ ch_W1, const float* __restrict__ ch_b1,
    const float* __restrict__ ch_W2, const float* __restrict__ ch_b2,
    const float* __restrict__ gn_w, const float* __restrict__ gn_b,
    const float* __restrict__ sp_W1, const float* __restrict__ sp_b1,
    const float* __restrict__ sp_W2, const float* __restrict__ sp_b2,
    const float* __restrict__ init_scale,
    const float* __restrict__ gms, const float* __restrict__ gw,
    const float* __restrict__ gb,
    float* __restrict__ spgOv, float* __restrict__ out)
{
    __shared__ float red[8][5][256];   // 40 KB: per-wave partials
    __shared__ float segA[5][256];     // 5 KB : reduced segment stats
    __shared__ float spgL[CAP * 16];   // 32 KB: per-node sp_gate(+tau)
    __shared__ float gap[512];         // 2 KB
    __shared__ float part[8][64];      // 2 KB
    __shared__ float hch[64];
    __shared__ float cA[512];          // 2 KB
    __shared__ float oA[512];          // 2 KB  -> ~85 KB total: 1 block/CU

    const int tid  = threadIdx.x;
    const int lane = tid & 63;
    const int w    = tid >> 6;        // 8 waves
    const int g    = lane & 15;
    const int q    = lane >> 4;
    const int h0   = q * 4;
    const int kk   = g & 7;
    const float tau = tanhf(init_scale[0]);

    // P1 per-lane weights (loop-invariant, hoisted)
    float gwv[4], gbv[4], b2v[4], swv[4], sbv[4], w1m[4], w1x[4], w1s[4], w2r[4];
#pragma unroll
    for (int j = 0; j < 4; ++j) {
        const int h = h0 + j;
        gwv[j] = gn_w[g * 16 + h];
        gbv[j] = gn_b[g * 16 + h];
        b2v[j] = sp_b2[h];
        swv[j] = sweight[h];
        sbv[j] = sbias[h];
        w1m[j] = sp_W1[h * 8 + kk];
        w1x[j] = sp_W1[(16 + h) * 8 + kk];
        w1s[j] = sp_W1[(32 + h) * 8 + kk];
        w2r[j] = sp_W2[kk * 16 + h];
    }
    const float b1k = sp_b1[kk];

    // P2 per-lane constants
    const int l2 = lane * 2;
    const int p0 = (lane >> 3) & 1;

    for (int r = 0; r < 4; ++r) {
        const int b = blockIdx.x * 4 + r;
        const int s = lower_bound_i(batch, NN, b);
        const int e = lower_bound_i(batch, NN, b + 1);
        const int cnt = e - s;

        __syncthreads();  // protect spgL/cA/oA from previous segment's P2

        // ---------------- Phase 1 ----------------
        float sc1[4] = {0.f,0.f,0.f,0.f}, sc2[4] = {0.f,0.f,0.f,0.f};
        float st1[4] = {0.f,0.f,0.f,0.f}, st2[4] = {0.f,0.f,0.f,0.f};
        float mxc[4] = {-INFINITY,-INFINITY,-INFINITY,-INFINITY};

        for (int n = s + w; n < e; n += 8) {
            const float* row = x + (size_t)n * CC + g * 32 + h0;
            const float4 c4 = *(const float4*)row;
            const float4 s4 = *(const float4*)(row + 16);
            float ca[4] = {c4.x, c4.y, c4.z, c4.w};
            float sa[4] = {s4.x, s4.y, s4.z, s4.w};

#pragma unroll
            for (int j = 0; j < 4; ++j) {
                sc1[j] += ca[j];
                sc2[j] = fmaf(ca[j], ca[j], sc2[j]);
                mxc[j] = fmaxf(mxc[j], ca[j]);
            }

            // groupnorm over h (local j + cross-row q)
            float ls = sa[0] + sa[1] + sa[2] + sa[3];
            float lq = fmaf(sa[0], sa[0], fmaf(sa[1], sa[1], fmaf(sa[2], sa[2], sa[3] * sa[3])));
            ls += __shfl_xor(ls, 16); ls += __shfl_xor(ls, 32);
            lq += __shfl_xor(lq, 16); lq += __shfl_xor(lq, 32);
            const float mu   = ls * 0.0625f;
            const float var  = lq * 0.0625f - mu * mu;
            const float rstd = rsqrtf(var + EPSF);
            float xn[4];
#pragma unroll
            for (int j = 0; j < 4; ++j)
                xn[j] = fmaf((sa[j] - mu) * rstd, gwv[j], gbv[j]);

            // ctx sum/max over g (bits 0-3, in-row DPP)
            float sm[4], mx[4];
#pragma unroll
            for (int j = 0; j < 4; ++j) {
                float v = xn[j];
                v = dppAdd<0xB1>(v); v = dppAdd<0x4E>(v);
                v = dppAdd<0x124>(v); v = dppAdd<0x128>(v);
                sm[j] = v;
                float m = xn[j];
                m = dppMax<0xB1>(m); m = dppMax<0x4E>(m);
                m = dppMax<0x124>(m); m = dppMax<0x128>(m);
                mx[j] = m;
            }
            float mean[4], ssq[4];
#pragma unroll
            for (int j = 0; j < 4; ++j) {
                mean[j] = sm[j] * 0.0625f;
                const float d = xn[j] - mean[j];
                float v = d * d;
                v = dppAdd<0xB1>(v); v = dppAdd<0x4E>(v);
                v = dppAdd<0x124>(v); v = dppAdd<0x128>(v);
                ssq[j] = v;
            }
            float stdc[4];
#pragma unroll
            for (int j = 0; j < 4; ++j) stdc[j] = sqrtf(ssq[j] * (1.0f / 15.0f));

            // spatial MLP: partial for k = kk, reduce over q
            float p = 0.f;
#pragma unroll
            for (int j = 0; j < 4; ++j) {
                p = fmaf(mean[j], w1m[j], p);
                p = fmaf(mx[j],   w1x[j], p);
                p = fmaf(stdc[j], w1s[j], p);
            }
            p += __shfl_xor(p, 16); p += __shfl_xor(p, 32);
            const float hsk = fmaxf(p + b1k, 0.0f);

            float spg[4];
#pragma unroll
            for (int j = 0; j < 4; ++j) {
                float t = hsk * w2r[j];
                t = dppAdd<0xB1>(t); t = dppAdd<0x4E>(t); t = dppAdd<0x141>(t);
                spg[j] = fmaf(sigmoidf(t + b2v[j]), 1.0f + swv[j], sbv[j]) + tau;
            }

#pragma unroll
            for (int j = 0; j < 4; ++j) {
                const float os = spg[j] * sa[j];
                st1[j] += os;
                st2[j] = fmaf(os, os, st2[j]);
            }

            if (g == 0) {
                const int idx = n - s;
                if (idx < CAP)
                    *(float4*)(&spgL[idx * 16 + h0]) = make_float4(spg[0], spg[1], spg[2], spg[3]);
                else
                    *(float4*)(spgOv + (size_t)n * 16 + h0) = make_float4(spg[0], spg[1], spg[2], spg[3]);
            }
        }

        const int ch = g * 16 + h0;
        *(float4*)&red[w][0][ch] = make_float4(sc1[0], sc1[1], sc1[2], sc1[3]);
        *(float4*)&red[w][1][ch] = make_float4(mxc[0], mxc[1], mxc[2], mxc[3]);
        *(float4*)&red[w][2][ch] = make_float4(sc2[0], sc2[1], sc2[2], sc2[3]);
        *(float4*)&red[w][3][ch] = make_float4(st1[0], st1[1], st1[2], st1[3]);
        *(float4*)&red[w][4][ch] = make_float4(st2[0], st2[1], st2[2], st2[3]);
        __syncthreads();
        if (tid < 256) {
            float a0 = 0.f, a2 = 0.f, a3 = 0.f, a4 = 0.f, a1 = -INFINITY;
#pragma unroll
            for (int ww = 0; ww < 8; ++ww) {
                a0 += red[ww][0][tid];
                a1 = fmaxf(a1, red[ww][1][tid]);
                a2 += red[ww][2][tid];
                a3 += red[ww][3][tid];
                a4 += red[ww][4][tid];
            }
            segA[0][tid] = a0; segA[1][tid] = a1; segA[2][tid] = a2;
            segA[3][tid] = a3; segA[4][tid] = a4;
        }
        __syncthreads();

        // ---------------- Phase F (inline) ----------------
        const float inv = 1.0f / (float)max(cnt, 1);
        if (tid < 256) {
            gap[tid] = segA[0][tid] * inv;
            gap[256 + tid] = (cnt > 0) ? segA[1][tid] : 0.0f;
        }
        __syncthreads();
        {
            const int t = tid & 63, pp = tid >> 6;
            float acc = 0.f;
            for (int i = pp * 64; i < pp * 64 + 64; ++i)
                acc = fmaf(gap[i], ch_W1[i * 64 + t], acc);
            part[pp][t] = acc;
        }
        __syncthreads();
        if (tid < 64) {
            float a = ch_b1[tid];
#pragma unroll
            for (int pp = 0; pp < 8; ++pp) a += part[pp][tid];
            hch[tid] = fmaxf(a, 0.0f);
        }
        __syncthreads();
        if (tid < 256) {
            const int c = tid, gg = c >> 4, h = c & 15;
            float acc = ch_b2[c];
            for (int k = 0; k < 64; ++k) acc = fmaf(hch[k], ch_W2[k * 256 + c], acc);
            const float chg = fmaf(sigmoidf(acc), 1.0f + cweight[h], cbias[h]);
            const float ct = chg + tau;
            const int colc = gg * 32 + h, cols = colc + 16;
            {
                const float S1 = segA[0][c], S2 = segA[2][c];
                const float m  = ct * S1 * inv;
                const float e2 = ct * ct * S2 * inv;
                const float smv = gms[colc];
                const float gv = fmaxf(e2 - m * m * smv * (2.0f - smv), 0.0f);
                const float A  = gw[colc] * rsqrtf(gv + EPSF);
                cA[colc] = A * ct;
                oA[colc] = gb[colc] - m * smv * A;
            }
            {
                const float T1 = segA[3][c], T2 = segA[4][c];
                const float m  = T1 * inv;
                const float e2 = T2 * inv;
                const float smv = gms[cols];
                const float gv = fmaxf(e2 - m * m * smv * (2.0f - smv), 0.0f);
                const float A  = gw[cols] * rsqrtf(gv + EPSF);
                cA[cols] = A;
                oA[cols] = gb[cols] - m * smv * A;
            }
        }
        __syncthreads();

        // ---------------- Phase 2 ----------------
        const float cf0 = cA[l2],       cf1 = cA[l2 + 1];
        const float cf2 = cA[128 + l2], cf3 = cA[129 + l2];
        const float cf4 = cA[256 + l2], cf5 = cA[257 + l2];
        const float cf6 = cA[384 + l2], cf7 = cA[385 + l2];
        const float of0 = oA[l2],       of1 = oA[l2 + 1];
        const float of2 = oA[128 + l2], of3 = oA[129 + l2];
        const float of4 = oA[256 + l2], of5 = oA[257 + l2];
        const float of6 = oA[384 + l2], of7 = oA[385 + l2];

        for (int n = s + w; n < e; n += 8) {
            const float2* r2 = (const float2*)(x + (size_t)n * CC);
            const float2 xa = r2[lane];
            const float2 xb = r2[64 + lane];
            const float2 xc = r2[128 + lane];
            const float2 xd = r2[192 + lane];
            const int idx = n - s;
            float2 sp;
            if (idx < CAP) sp = *(const float2*)(&spgL[idx * 16 + (l2 & 15)]);
            else           sp = *(const float2*)(spgOv + (size_t)n * 16 + (l2 & 15));
            const float me = p0 ? sp.x : 1.0f;
            const float mo = p0 ? sp.y : 1.0f;

            const float v0 = fmaf(cf0 * me, xa.x, of0);
            const float v1 = fmaf(cf1 * mo, xa.y, of1);
            const float v2 = fmaf(cf2 * me, xb.x, of2);
            const float v3 = fmaf(cf3 * mo, xb.y, of3);
            const float v4 = fmaf(cf4 * me, xc.x, of4);
            const float v5 = fmaf(cf5 * mo, xc.y, of5);
            const float v6 = fmaf(cf6 * me, xd.x, of6);
            const float v7 = fmaf(cf7 * mo, xd.y, of7);

            f32x4* o4 = (f32x4*)(out + (size_t)n * CC);
            f32x4 pa = {v0, v4, v1, v5};
            f32x4 pb = {v2, v6, v3, v7};
            __builtin_nontemporal_store(pa, &o4[lane]);
            __builtin_nontemporal_store(pb, &o4[64 + lane]);
        }
    }
}

extern "C" void kernel_launch(void* const* d_in, const int* in_sizes, int n_in,
                              void* d_out, int out_size, void* d_ws, size_t ws_size,
                              hipStream_t stream) {
    (void)in_sizes; (void)n_in; (void)out_size; (void)ws_size;
    const float* x        = (const float*)d_in[0];
    const int*   batch    = (const int*)d_in[1];
    const float* cweight  = (const float*)d_in[3];
    const float* cbias    = (const float*)d_in[4];
    const float* sweight  = (const float*)d_in[5];
    const float* sbias    = (const float*)d_in[6];
    const float* ch_W1    = (const float*)d_in[7];
    const float* ch_b1    = (const float*)d_in[8];
    const float* ch_W2    = (const float*)d_in[9];
    const float* ch_b2    = (const float*)d_in[10];
    const float* gn_w     = (const float*)d_in[11];
    const float* gn_b     = (const float*)d_in[12];
    const float* sp_W1    = (const float*)d_in[13];
    const float* sp_b1    = (const float*)d_in[14];
    const float* sp_W2    = (const float*)d_in[15];
    const float* sp_b2    = (const float*)d_in[16];
    const float* init_sc  = (const float*)d_in[17];
    const float* gnw      = (const float*)d_in[18];
    const float* gnb      = (const float*)d_in[19];
    const float* gms      = (const float*)d_in[20];

    float* spgOv = (float*)d_ws;   // NN*16 floats worst-case overflow
    float* outp  = (float*)d_out;

    kFused<<<BB / 4, 512, 0, stream>>>(x, batch, cweight, cbias, sweight, sbias,
                                       ch_W1, ch_b1, ch_W2, ch_b2, gn_w, gn_b,
                                       sp_W1, sp_b1, sp_W2, sp_b2, init_sc,
                                       gms, gnw, gnb, spgOv, outp);
}